// Round 8
// baseline (776.917 us; speedup 1.0000x reference)
//
#include <hip/hip_runtime.h>
#include <cmath>

typedef short short8 __attribute__((ext_vector_type(8)));
typedef float floatx4 __attribute__((ext_vector_type(4)));

#define T_LEN 4096
#define HC 256
#define NPOS (32 * 4096)
#define OUT_ELEMS (32 * 4 * 4096)

__device__ __forceinline__ ushort f2bf(float f) {
    uint u = __float_as_uint(f);
    u += 0x7FFFu + ((u >> 16) & 1u);
    return (ushort)(u >> 16);
}
__device__ __forceinline__ float bf2f(ushort u) {
    return __uint_as_float(((uint)u) << 16);
}
__device__ __forceinline__ uint addbf2(uint a, uint b) {
    const float lo = bf2f((ushort)(a & 0xffffu)) + bf2f((ushort)(b & 0xffffu));
    const float hi = bf2f((ushort)(a >> 16)) + bf2f((ushort)(b >> 16));
    return (uint)f2bf(lo) | ((uint)f2bf(hi) << 16);
}
// fast tanh-form gelu: 8 instr, no branches; |err vs exact-erf gelu| <~1.5e-3
__device__ __forceinline__ float gelu_f(float x) {
    const float x2 = x * x;
    const float w = fmaf(0.044715f * x2, x, x);
    const float e = __builtin_amdgcn_exp2f(2.3022084f * w);
    const float r = __builtin_amdgcn_rcpf(1.f + e);
    return fmaf(-x, r, x);
}
__device__ __forceinline__ float softplus_f(float x) {
    return (x > 20.f) ? x : log1pf(expf(x));
}
__device__ __forceinline__ void load4bf(const ushort* p, float m, float* o) {
    uint2 r = *(const uint2*)p;
    o[0] = bf2f((ushort)(r.x & 0xffffu)) * m;
    o[1] = bf2f((ushort)(r.x >> 16)) * m;
    o[2] = bf2f((ushort)(r.y & 0xffffu)) * m;
    o[3] = bf2f((ushort)(r.y >> 16)) * m;
}

// ---------------------------------------------------------------- prep ----
__global__ __launch_bounds__(256) void prep_kernel(
    const float* __restrict__ cw, const float* __restrict__ pw,
    ushort* __restrict__ wbf, ushort* __restrict__ pwbf)
{
    int idx = blockIdx.x * 256 + threadIdx.x;
    if (idx < 4 * 256 * 256) {
        wbf[idx] = f2bf(cw[idx]);
    } else if (idx < 4 * 256 * 256 + 64 * 256) {
        int j = idx - 4 * 256 * 256;
        int row = j >> 8, c = j & 255;
        pwbf[j] = (row < 58) ? f2bf(pw[row * 256 + c]) : (ushort)0;
    }
}

// ----------------------------------------------------------------- pre ----
__global__ __launch_bounds__(256) void pre_kernel(
    const float* __restrict__ x, const float* __restrict__ mask,
    const float* __restrict__ pre_w, const float* __restrict__ pre_b,
    ushort* __restrict__ h, float* __restrict__ out)
{
    const int t = threadIdx.x;
    const int p0 = blockIdx.x * 2;
    const int p = p0 + (t >> 7);
    const int o = (t & 127) * 2;
    const int b = p >> 12;
    const int tt = p & 4095;
    const float xa = x[b * 16384 + tt];
    const float xb = x[b * 16384 + 4096 + tt];
    const float4 w = *(const float4*)(pre_w + 2 * o);
    const float v0 = w.x * xa + w.y * xb + pre_b[o];
    const float v1 = w.z * xa + w.w * xb + pre_b[o + 1];
    const uint pk = (uint)f2bf(v0) | ((uint)f2bf(v1) << 16);
    *(uint*)(h + (size_t)p * HC + o) = pk;
    if (t < 4) {
        const int pp = p0 + (t >> 1);
        const int bb = pp >> 12, t2 = pp & 4095;
        const int ch = t & 1;
        out[bb * 16384 + ch * 4096 + t2] = x[bb * 16384 + ch * 4096 + t2] * mask[bb * 4096 + t2];
    }
    if (blockIdx.x == 0 && t >= 64 && t < 96) out[OUT_ELEMS + (t - 64)] = 0.f;
}

// ---------------------------------------------------------------- dwln ----
// (unchanged — known good) dwconv(dil)+LN(n1)+gelu -> yg (bf16).
__global__ __launch_bounds__(256, 6) void dwln_kernel(
    const ushort* __restrict__ hin, ushort* __restrict__ yg,
    const float* __restrict__ sep_w, const float* __restrict__ sep_b,
    const float* __restrict__ n1g, const float* __restrict__ n1b,
    const float* __restrict__ mask, int dil)
{
    const int tid = threadIdx.x;
    const int lane = tid & 63;
    const int wv = tid >> 6;
    const int P = blockIdx.x;
    const int L = (P & 7) * 512 + (P >> 3);
    const int b = L >> 7;
    const int t0 = (L & 127) << 5;
    const float* maskb = mask + b * T_LEN;
    const size_t hbase = (size_t)b * T_LEN * HC;

    const int c0 = lane * 4;
    float sw[12];
    *(float4*)(sw + 0) = *(const float4*)(sep_w + c0 * 3 + 0);
    *(float4*)(sw + 4) = *(const float4*)(sep_w + c0 * 3 + 4);
    *(float4*)(sw + 8) = *(const float4*)(sep_w + c0 * 3 + 8);
    float sbv[4], g1v[4], b1v[4];
    *(float4*)sbv = *(const float4*)(sep_b + c0);
    *(float4*)g1v = *(const float4*)(n1g + c0);
    *(float4*)b1v = *(const float4*)(n1b + c0);

    for (int mm = 0; mm < 8; mm += 2) {
        float v[2][4];
        float s[2], q[2];
        #pragma unroll
        for (int u = 0; u < 2; ++u) {
            const int t = t0 + wv * 8 + mm + u;
            float hm[4] = {0.f, 0.f, 0.f, 0.f};
            float hp[4] = {0.f, 0.f, 0.f, 0.f};
            float hc[4];
            load4bf(hin + hbase + (size_t)t * HC + c0, maskb[t], hc);
            if (t >= dil)
                load4bf(hin + hbase + (size_t)(t - dil) * HC + c0, maskb[t - dil], hm);
            if (t + dil < T_LEN)
                load4bf(hin + hbase + (size_t)(t + dil) * HC + c0, maskb[t + dil], hp);
            s[u] = 0.f; q[u] = 0.f;
            #pragma unroll
            for (int j = 0; j < 4; ++j) {
                const float vv = sw[3 * j] * hm[j] + sw[3 * j + 1] * hc[j]
                               + sw[3 * j + 2] * hp[j] + sbv[j];
                v[u][j] = vv;
                s[u] += vv;
                q[u] += vv * vv;
            }
        }
        #pragma unroll
        for (int d = 32; d > 0; d >>= 1) {
            s[0] += __shfl_xor(s[0], d, 64);
            q[0] += __shfl_xor(q[0], d, 64);
            s[1] += __shfl_xor(s[1], d, 64);
            q[1] += __shfl_xor(q[1], d, 64);
        }
        #pragma unroll
        for (int u = 0; u < 2; ++u) {
            const int t = t0 + wv * 8 + mm + u;
            const float mean = s[u] * (1.f / 256.f);
            const float var = q[u] * (1.f / 256.f) - mean * mean;
            const float rs = rsqrtf(var + 1e-5f);
            const float y0 = gelu_f((v[u][0] - mean) * rs * g1v[0] + b1v[0]);
            const float y1 = gelu_f((v[u][1] - mean) * rs * g1v[1] + b1v[1]);
            const float y2 = gelu_f((v[u][2] - mean) * rs * g1v[2] + b1v[2]);
            const float y3 = gelu_f((v[u][3] - mean) * rs * g1v[3] + b1v[3]);
            const uint pk0 = (uint)f2bf(y0) | ((uint)f2bf(y1) << 16);
            const uint pk1 = (uint)f2bf(y2) | ((uint)f2bf(y3) << 16);
            *(uint2*)(yg + hbase + (size_t)t * HC + c0) = make_uint2(pk0, pk1);
        }
    }
}

// ---------------------------------------------------------------- gemm ----
// M=64 tile (grid 2048). Wave = (M-half: 32 rows) x (N-half: 128 outs).
// bounds(256,2): ~256 unified regs/wave so the compiler can hold multiple
// kt of B-fragments in flight (at (256,3) it stopped at 84 arch VGPRs —
// not enough prefetch depth, K-loop re-exposed L2 latency every kt).
// Residual prefetched BEFORE the K-loop to ride under the MFMA phase.
__global__ __launch_bounds__(256, 2) void gemm_kernel(
    const ushort* __restrict__ yg, const ushort* __restrict__ hin,
    ushort* __restrict__ hout, const ushort* __restrict__ wbf,
    const float* __restrict__ conv1_b,
    const float* __restrict__ n2g, const float* __restrict__ n2b)
{
    __shared__ __align__(16) ushort ylds[64 * 264];
    __shared__ float ssum[64][2];
    __shared__ float ssq[64][2];

    const int tid = threadIdx.x;
    const int lane = tid & 63;
    const int wv = tid >> 6;
    const int P = blockIdx.x;
    const int L = (P & 7) * 256 + (P >> 3);
    const int b = L >> 6;
    const int t0 = (L & 63) << 6;
    const size_t hbase = (size_t)b * T_LEN * HC;

    // ---- stage y tile: 64 rows x 256 ch (8 outstanding 16B loads/thread) ----
    #pragma unroll
    for (int jj = 0; jj < 8; ++jj) {
        const int idx = jj * 256 + tid;           // 2048 chunks of 16B
        const int row = idx >> 5, seg = idx & 31;
        short8 v = *(const short8*)(yg + hbase + (size_t)(t0 + row) * HC + seg * 8);
        *(short8*)(&ylds[row * 264 + seg * 8]) = v;
    }

    // ---- residual prefetch: overlaps staging-wait + K-loop ----
    uint4 hv[8];
    #pragma unroll
    for (int jj = 0; jj < 8; ++jj) {
        const int idx = jj * 256 + tid;
        const int row = idx >> 5, seg = idx & 31;
        hv[jj] = *(const uint4*)(hin + hbase + (size_t)(t0 + row) * HC + seg * 8);
    }
    __syncthreads();

    // ---- MFMA: wave (mh,nh): rows mh*32..+31, outs nh*128..+127 ----
    const int lw = lane & 15;
    const int quad = lane >> 4;
    const int mh = wv >> 1;
    const int nh = wv & 1;
    floatx4 acc[2][8];
    #pragma unroll
    for (int m = 0; m < 2; ++m)
        #pragma unroll
        for (int n = 0; n < 8; ++n) acc[m][n] = (floatx4){0.f, 0.f, 0.f, 0.f};

    const ushort* wb = wbf + (nh * 128 + lw) * 256 + quad * 8;
    #pragma unroll
    for (int kt = 0; kt < 8; ++kt) {
        short8 a0 = *(short8*)(&ylds[(mh * 32 + lw) * 264 + kt * 32 + quad * 8]);
        short8 a1 = *(short8*)(&ylds[(mh * 32 + 16 + lw) * 264 + kt * 32 + quad * 8]);
        #pragma unroll
        for (int n = 0; n < 8; ++n) {
            short8 bb = *(const short8*)(wb + n * 4096 + kt * 32);
            acc[0][n] = __builtin_amdgcn_mfma_f32_16x16x32_bf16(a0, bb, acc[0][n], 0, 0, 0);
            acc[1][n] = __builtin_amdgcn_mfma_f32_16x16x32_bf16(a1, bb, acc[1][n], 0, 0, 0);
        }
    }

    // ---- epilogue: bias + split LN(n2) over col halves ----
    float sum[2][4] = {{0, 0, 0, 0}, {0, 0, 0, 0}};
    float sq[2][4] = {{0, 0, 0, 0}, {0, 0, 0, 0}};
    #pragma unroll
    for (int n = 0; n < 8; ++n) {
        const float cb = conv1_b[nh * 128 + n * 16 + lw];
        #pragma unroll
        for (int m = 0; m < 2; ++m)
            #pragma unroll
            for (int r = 0; r < 4; ++r) {
                const float val = acc[m][n][r] + cb;
                acc[m][n][r] = val;
                sum[m][r] += val;
                sq[m][r] += val * val;
            }
    }
    #pragma unroll
    for (int d = 1; d < 16; d <<= 1) {
        #pragma unroll
        for (int m = 0; m < 2; ++m)
            #pragma unroll
            for (int r = 0; r < 4; ++r) {
                sum[m][r] += __shfl_xor(sum[m][r], d, 64);
                sq[m][r] += __shfl_xor(sq[m][r], d, 64);
            }
    }
    if (lw == 0) {
        #pragma unroll
        for (int m = 0; m < 2; ++m)
            #pragma unroll
            for (int r = 0; r < 4; ++r) {
                ssum[mh * 32 + m * 16 + quad * 4 + r][nh] = sum[m][r];
                ssq[mh * 32 + m * 16 + quad * 4 + r][nh] = sq[m][r];
            }
    }
    __syncthreads();   // also guarantees all ylds a-frag reads are done

    float mean[2][4], rsv[2][4];
    #pragma unroll
    for (int m = 0; m < 2; ++m)
        #pragma unroll
        for (int r = 0; r < 4; ++r) {
            const int row = mh * 32 + m * 16 + quad * 4 + r;
            const float s = ssum[row][0] + ssum[row][1];
            const float q = ssq[row][0] + ssq[row][1];
            mean[m][r] = s * (1.f / 256.f);
            const float var = q * (1.f / 256.f) - mean[m][r] * mean[m][r];
            rsv[m][r] = rsqrtf(var + 1e-5f);
        }
    #pragma unroll
    for (int n = 0; n < 8; ++n) {
        const int o = nh * 128 + n * 16 + lw;
        const float g2 = n2g[o], b2 = n2b[o];
        #pragma unroll
        for (int m = 0; m < 2; ++m)
            #pragma unroll
            for (int r = 0; r < 4; ++r) {
                const int row = mh * 32 + m * 16 + quad * 4 + r;
                const float y = gelu_f((acc[m][n][r] - mean[m][r]) * rsv[m][r] * g2 + b2);
                ylds[row * 264 + o] = f2bf(y);
            }
    }
    __syncthreads();

    // ---- vectorized residual + store (in-place over yg is safe) ----
    #pragma unroll
    for (int jj = 0; jj < 8; ++jj) {
        const int idx = jj * 256 + tid;
        const int row = idx >> 5, seg = idx & 31;
        const size_t g = hbase + (size_t)(t0 + row) * HC + seg * 8;
        const uint4 yv = *(const uint4*)(&ylds[row * 264 + seg * 8]);
        uint4 ov;
        ov.x = addbf2(yv.x, hv[jj].x);
        ov.y = addbf2(yv.y, hv[jj].y);
        ov.z = addbf2(yv.z, hv[jj].z);
        ov.w = addbf2(yv.w, hv[jj].w);
        *(uint4*)(hout + g) = ov;
    }
}

// ---------------------------------------------------------- proj+spline ----
__global__ __launch_bounds__(256) void proj_kernel(
    const ushort* __restrict__ hin, const ushort* __restrict__ pwbf,
    const float* __restrict__ projb, const float* __restrict__ x,
    const float* __restrict__ mask, float* __restrict__ out)
{
    __shared__ __align__(16) ushort alds[64 * 264];
    __shared__ float slds[64 * 65];
    __shared__ float red[4];

    const int tid = threadIdx.x;
    const int lane = tid & 63;
    const int wv = tid >> 6;
    const int blk = blockIdx.x;
    const int b = blk >> 6;
    const int t0 = (blk & 63) << 6;
    const size_t hbase = (size_t)b * T_LEN * HC;

    #pragma unroll
    for (int jj = 0; jj < 8; ++jj) {
        const int idx = jj * 256 + tid;
        const int row = idx >> 5, seg = idx & 31;
        short8 v = *(const short8*)(hin + hbase + (size_t)(t0 + row) * HC + seg * 8);
        *(short8*)(&alds[row * 264 + seg * 8]) = v;
    }
    __syncthreads();

    const int lw = lane & 15;
    const int quad = lane >> 4;
    floatx4 acc[4];
    #pragma unroll
    for (int n = 0; n < 4; ++n) acc[n] = (floatx4){0.f, 0.f, 0.f, 0.f};
    #pragma unroll
    for (int kt = 0; kt < 8; ++kt) {
        short8 a = *(short8*)(&alds[(wv * 16 + lw) * 264 + kt * 32 + quad * 8]);
        #pragma unroll
        for (int n = 0; n < 4; ++n) {
            short8 bb = *(const short8*)(pwbf + (n * 16 + lw) * 256 + kt * 32 + quad * 8);
            acc[n] = __builtin_amdgcn_mfma_f32_16x16x32_bf16(a, bb, acc[n], 0, 0, 0);
        }
    }
    #pragma unroll
    for (int n = 0; n < 4; ++n) {
        const int o = n * 16 + lw;
        const float pb = (o < 58) ? projb[o] : 0.f;
        #pragma unroll
        for (int r = 0; r < 4; ++r) {
            const int row = wv * 16 + quad * 4 + r;
            const float mv = mask[b * T_LEN + t0 + row];
            slds[row * 65 + o] = acc[n][r] * mv + pb;
        }
    }
    __syncthreads();

    float contrib = 0.f;
    if (tid < 128) {
        const int pos = tid >> 1;
        const int ch = tid & 1;
        const int t = t0 + pos;
        float sv[29];
        #pragma unroll
        for (int j = 0; j < 29; ++j) sv[j] = slds[pos * 65 + ch * 29 + j];
        const float x1 = x[b * 16384 + (2 + ch) * 4096 + t];

        const float SC = 0.0625f;
        float cwv[11], wdv[10], chv[11], htv[10], dvv[11];
        {
            float u[10];
            float mx = -1e30f;
            #pragma unroll
            for (int j = 0; j < 10; ++j) { u[j] = sv[j] * SC; mx = fmaxf(mx, u[j]); }
            float ssm = 0.f;
            #pragma unroll
            for (int j = 0; j < 10; ++j) { u[j] = expf(u[j] - mx); ssm += u[j]; }
            const float inv = 1.f / ssm;
            float cum = 0.f;
            cwv[0] = -5.f;
            #pragma unroll
            for (int j = 0; j < 10; ++j) {
                cum += 0.001f + 0.99f * u[j] * inv;
                cwv[j + 1] = 10.f * cum - 5.f;
            }
            cwv[10] = 5.f;
            #pragma unroll
            for (int j = 0; j < 10; ++j) wdv[j] = cwv[j + 1] - cwv[j];
        }
        {
            float u[10];
            float mx = -1e30f;
            #pragma unroll
            for (int j = 0; j < 10; ++j) { u[j] = sv[10 + j] * SC; mx = fmaxf(mx, u[j]); }
            float ssm = 0.f;
            #pragma unroll
            for (int j = 0; j < 10; ++j) { u[j] = expf(u[j] - mx); ssm += u[j]; }
            const float inv = 1.f / ssm;
            float cum = 0.f;
            chv[0] = -5.f;
            #pragma unroll
            for (int j = 0; j < 10; ++j) {
                cum += 0.001f + 0.99f * u[j] * inv;
                chv[j + 1] = 10.f * cum - 5.f;
            }
            chv[10] = 5.f;
            #pragma unroll
            for (int j = 0; j < 10; ++j) htv[j] = chv[j + 1] - chv[j];
        }
        dvv[0] = 1.f;
        dvv[10] = 1.f;
        #pragma unroll
        for (int j = 1; j <= 9; ++j) dvv[j] = 0.001f + softplus_f(sv[19 + j]);

        const bool inside = (x1 >= -5.f) && (x1 <= 5.f);
        const float xc = fminf(fmaxf(x1, -5.f), 5.f);
        float in_cw = cwv[0], in_w = wdv[0], in_ch = chv[0], in_h = htv[0];
        float dk = dvv[0], dk1 = dvv[1];
        #pragma unroll
        for (int j = 1; j < 10; ++j) {
            const bool ge = (xc >= cwv[j]);
            in_cw = ge ? cwv[j] : in_cw;
            in_w  = ge ? wdv[j] : in_w;
            in_ch = ge ? chv[j] : in_ch;
            in_h  = ge ? htv[j] : in_h;
            dk    = ge ? dvv[j] : dk;
            dk1   = ge ? dvv[j + 1] : dk1;
        }
        const float th = (xc - in_cw) / in_w;
        const float t1m = th * (1.f - th);
        const float dl = in_h / in_w;
        const float num = in_h * (dl * th * th + dk * t1m);
        const float den = dl + (dk + dk1 - 2.f * dl) * t1m;
        float yv = in_ch + num / den;
        const float omt = 1.f - th;
        const float dnum = dl * dl * (dk1 * th * th + 2.f * dl * t1m + dk * omt * omt);
        float lad = logf(dnum) - 2.f * logf(den);
        if (!inside) { yv = x1; lad = 0.f; }
        const float mv = mask[b * T_LEN + t];
        out[b * 16384 + (2 + ch) * 4096 + t] = yv * mv;
        contrib = lad * mv;
    }
    #pragma unroll
    for (int d = 32; d > 0; d >>= 1) contrib += __shfl_xor(contrib, d, 64);
    if (lane == 0) red[wv] = contrib;
    __syncthreads();
    if (tid == 0) atomicAdd(out + OUT_ELEMS + b, red[0] + red[1] + red[2] + red[3]);
}

// -------------------------------------------------------------- launch ----
extern "C" void kernel_launch(void* const* d_in, const int* in_sizes, int n_in,
                              void* d_out, int out_size, void* d_ws, size_t ws_size,
                              hipStream_t stream) {
    const float* x      = (const float*)d_in[0];
    const float* mask   = (const float*)d_in[1];
    const float* pre_w  = (const float*)d_in[2];
    const float* pre_b  = (const float*)d_in[3];
    const float* sep_w  = (const float*)d_in[4];
    const float* sep_b  = (const float*)d_in[5];
    const float* conv1w = (const float*)d_in[6];
    const float* conv1b = (const float*)d_in[7];
    const float* n1g    = (const float*)d_in[8];
    const float* n1b    = (const float*)d_in[9];
    const float* n2g    = (const float*)d_in[10];
    const float* n2b    = (const float*)d_in[11];
    const float* projw  = (const float*)d_in[12];
    const float* projb  = (const float*)d_in[13];
    float* out = (float*)d_out;

    ushort* h0   = (ushort*)d_ws;
    ushort* h1   = h0 + (size_t)NPOS * HC;
    ushort* wbf  = h1 + (size_t)NPOS * HC;
    ushort* pwbf = wbf + 4 * 256 * 256;

    prep_kernel<<<1088, 256, 0, stream>>>(conv1w, projw, wbf, pwbf);
    pre_kernel<<<NPOS / 2, 256, 0, stream>>>(x, mask, pre_w, pre_b, h0, out);

    int dil = 1;
    ushort* src = h0;   // current h
    ushort* dst = h1;   // y staging, then overwritten in-place with h_next
    for (int i = 0; i < 4; ++i) {
        dwln_kernel<<<4096, 256, 0, stream>>>(src, dst,
            sep_w + i * 768, sep_b + i * 256,
            n1g + i * 256, n1b + i * 256, mask, dil);
        gemm_kernel<<<2048, 256, 0, stream>>>(dst, src, dst, wbf + i * 65536,
            conv1b + i * 256, n2g + i * 256, n2b + i * 256);
        dil *= 3;
        ushort* tmp = src; src = dst; dst = tmp;
    }
    proj_kernel<<<2048, 256, 0, stream>>>(src, pwbf, projb, x, mask, out);
}

// Round 9
// 696.529 us; speedup vs baseline: 1.1154x; 1.1154x over previous
//
#include <hip/hip_runtime.h>
#include <cmath>

typedef short short8 __attribute__((ext_vector_type(8)));
typedef float floatx4 __attribute__((ext_vector_type(4)));

#define T_LEN 4096
#define HC 256
#define NPOS (32 * 4096)
#define OUT_ELEMS (32 * 4 * 4096)

__device__ __forceinline__ ushort f2bf(float f) {
    uint u = __float_as_uint(f);
    u += 0x7FFFu + ((u >> 16) & 1u);
    return (ushort)(u >> 16);
}
__device__ __forceinline__ float bf2f(ushort u) {
    return __uint_as_float(((uint)u) << 16);
}
__device__ __forceinline__ uint addbf2(uint a, uint b) {
    const float lo = bf2f((ushort)(a & 0xffffu)) + bf2f((ushort)(b & 0xffffu));
    const float hi = bf2f((ushort)(a >> 16)) + bf2f((ushort)(b >> 16));
    return (uint)f2bf(lo) | ((uint)f2bf(hi) << 16);
}
// fast tanh-form gelu: 8 instr, no branches; |err vs exact-erf gelu| <~1.5e-3
__device__ __forceinline__ float gelu_f(float x) {
    const float x2 = x * x;
    const float w = fmaf(0.044715f * x2, x, x);
    const float e = __builtin_amdgcn_exp2f(2.3022084f * w);
    const float r = __builtin_amdgcn_rcpf(1.f + e);
    return fmaf(-x, r, x);
}
__device__ __forceinline__ float softplus_f(float x) {
    return (x > 20.f) ? x : log1pf(expf(x));
}
__device__ __forceinline__ void load4bf(const ushort* p, float m, float* o) {
    uint2 r = *(const uint2*)p;
    o[0] = bf2f((ushort)(r.x & 0xffffu)) * m;
    o[1] = bf2f((ushort)(r.x >> 16)) * m;
    o[2] = bf2f((ushort)(r.y & 0xffffu)) * m;
    o[3] = bf2f((ushort)(r.y >> 16)) * m;
}

// ---------------------------------------------------------------- prep ----
__global__ __launch_bounds__(256) void prep_kernel(
    const float* __restrict__ cw, const float* __restrict__ pw,
    ushort* __restrict__ wbf, ushort* __restrict__ pwbf)
{
    int idx = blockIdx.x * 256 + threadIdx.x;
    if (idx < 4 * 256 * 256) {
        wbf[idx] = f2bf(cw[idx]);
    } else if (idx < 4 * 256 * 256 + 64 * 256) {
        int j = idx - 4 * 256 * 256;
        int row = j >> 8, c = j & 255;
        pwbf[j] = (row < 58) ? f2bf(pw[row * 256 + c]) : (ushort)0;
    }
}

// ----------------------------------------------------------------- pre ----
__global__ __launch_bounds__(256) void pre_kernel(
    const float* __restrict__ x, const float* __restrict__ mask,
    const float* __restrict__ pre_w, const float* __restrict__ pre_b,
    ushort* __restrict__ h, float* __restrict__ out)
{
    const int t = threadIdx.x;
    const int p0 = blockIdx.x * 2;
    const int p = p0 + (t >> 7);
    const int o = (t & 127) * 2;
    const int b = p >> 12;
    const int tt = p & 4095;
    const float xa = x[b * 16384 + tt];
    const float xb = x[b * 16384 + 4096 + tt];
    const float4 w = *(const float4*)(pre_w + 2 * o);
    const float v0 = w.x * xa + w.y * xb + pre_b[o];
    const float v1 = w.z * xa + w.w * xb + pre_b[o + 1];
    const uint pk = (uint)f2bf(v0) | ((uint)f2bf(v1) << 16);
    *(uint*)(h + (size_t)p * HC + o) = pk;
    if (t < 4) {
        const int pp = p0 + (t >> 1);
        const int bb = pp >> 12, t2 = pp & 4095;
        const int ch = t & 1;
        out[bb * 16384 + ch * 4096 + t2] = x[bb * 16384 + ch * 4096 + t2] * mask[bb * 4096 + t2];
    }
    if (blockIdx.x == 0 && t >= 64 && t < 96) out[OUT_ELEMS + (t - 64)] = 0.f;
}

// ---------------------------------------------------------------- dwln ----
// (unchanged — known good) dwconv(dil)+LN(n1)+gelu -> yg (bf16).
__global__ __launch_bounds__(256, 6) void dwln_kernel(
    const ushort* __restrict__ hin, ushort* __restrict__ yg,
    const float* __restrict__ sep_w, const float* __restrict__ sep_b,
    const float* __restrict__ n1g, const float* __restrict__ n1b,
    const float* __restrict__ mask, int dil)
{
    const int tid = threadIdx.x;
    const int lane = tid & 63;
    const int wv = tid >> 6;
    const int P = blockIdx.x;
    const int L = (P & 7) * 512 + (P >> 3);
    const int b = L >> 7;
    const int t0 = (L & 127) << 5;
    const float* maskb = mask + b * T_LEN;
    const size_t hbase = (size_t)b * T_LEN * HC;

    const int c0 = lane * 4;
    float sw[12];
    *(float4*)(sw + 0) = *(const float4*)(sep_w + c0 * 3 + 0);
    *(float4*)(sw + 4) = *(const float4*)(sep_w + c0 * 3 + 4);
    *(float4*)(sw + 8) = *(const float4*)(sep_w + c0 * 3 + 8);
    float sbv[4], g1v[4], b1v[4];
    *(float4*)sbv = *(const float4*)(sep_b + c0);
    *(float4*)g1v = *(const float4*)(n1g + c0);
    *(float4*)b1v = *(const float4*)(n1b + c0);

    for (int mm = 0; mm < 8; mm += 2) {
        float v[2][4];
        float s[2], q[2];
        #pragma unroll
        for (int u = 0; u < 2; ++u) {
            const int t = t0 + wv * 8 + mm + u;
            float hm[4] = {0.f, 0.f, 0.f, 0.f};
            float hp[4] = {0.f, 0.f, 0.f, 0.f};
            float hc[4];
            load4bf(hin + hbase + (size_t)t * HC + c0, maskb[t], hc);
            if (t >= dil)
                load4bf(hin + hbase + (size_t)(t - dil) * HC + c0, maskb[t - dil], hm);
            if (t + dil < T_LEN)
                load4bf(hin + hbase + (size_t)(t + dil) * HC + c0, maskb[t + dil], hp);
            s[u] = 0.f; q[u] = 0.f;
            #pragma unroll
            for (int j = 0; j < 4; ++j) {
                const float vv = sw[3 * j] * hm[j] + sw[3 * j + 1] * hc[j]
                               + sw[3 * j + 2] * hp[j] + sbv[j];
                v[u][j] = vv;
                s[u] += vv;
                q[u] += vv * vv;
            }
        }
        #pragma unroll
        for (int d = 32; d > 0; d >>= 1) {
            s[0] += __shfl_xor(s[0], d, 64);
            q[0] += __shfl_xor(q[0], d, 64);
            s[1] += __shfl_xor(s[1], d, 64);
            q[1] += __shfl_xor(q[1], d, 64);
        }
        #pragma unroll
        for (int u = 0; u < 2; ++u) {
            const int t = t0 + wv * 8 + mm + u;
            const float mean = s[u] * (1.f / 256.f);
            const float var = q[u] * (1.f / 256.f) - mean * mean;
            const float rs = rsqrtf(var + 1e-5f);
            const float y0 = gelu_f((v[u][0] - mean) * rs * g1v[0] + b1v[0]);
            const float y1 = gelu_f((v[u][1] - mean) * rs * g1v[1] + b1v[1]);
            const float y2 = gelu_f((v[u][2] - mean) * rs * g1v[2] + b1v[2]);
            const float y3 = gelu_f((v[u][3] - mean) * rs * g1v[3] + b1v[3]);
            const uint pk0 = (uint)f2bf(y0) | ((uint)f2bf(y1) << 16);
            const uint pk1 = (uint)f2bf(y2) | ((uint)f2bf(y3) << 16);
            *(uint2*)(yg + hbase + (size_t)t * HC + c0) = make_uint2(pk0, pk1);
        }
    }
}

// ---------------------------------------------------------------- gemm ----
// M=64 tile (grid 2048). Wave = (M-half: 32 rows) x (N-half: 128 outs).
// NO LDS staging / no staging barrier: each wave reads its OWN A-fragments
// directly from yg (L2-hot — same XCD swizzle as dwln wrote them). ylds is
// only used in the epilogue for the store-coalescing exchange. bounds(256,3)
// (R7 config — R8 showed (256,2) regresses).
__global__ __launch_bounds__(256, 3) void gemm_kernel(
    const ushort* __restrict__ yg, const ushort* __restrict__ hin,
    ushort* __restrict__ hout, const ushort* __restrict__ wbf,
    const float* __restrict__ conv1_b,
    const float* __restrict__ n2g, const float* __restrict__ n2b)
{
    __shared__ __align__(16) ushort ylds[64 * 264];
    __shared__ float ssum[64][2];
    __shared__ float ssq[64][2];

    const int tid = threadIdx.x;
    const int lane = tid & 63;
    const int wv = tid >> 6;
    const int P = blockIdx.x;
    const int L = (P & 7) * 256 + (P >> 3);
    const int b = L >> 6;
    const int t0 = (L & 63) << 6;
    const size_t hbase = (size_t)b * T_LEN * HC;

    // ---- MFMA: wave (mh,nh): rows mh*32..+31, outs nh*128..+127 ----
    const int lw = lane & 15;
    const int quad = lane >> 4;
    const int mh = wv >> 1;
    const int nh = wv & 1;
    floatx4 acc[2][8];
    #pragma unroll
    for (int m = 0; m < 2; ++m)
        #pragma unroll
        for (int n = 0; n < 8; ++n) acc[m][n] = (floatx4){0.f, 0.f, 0.f, 0.f};

    const ushort* wb = wbf + (nh * 128 + lw) * 256 + quad * 8;
    const ushort* ya0 = yg + hbase + (size_t)(t0 + mh * 32 + lw) * HC + quad * 8;
    const ushort* ya1 = ya0 + 16 * HC;
    #pragma unroll
    for (int kt = 0; kt < 8; ++kt) {
        short8 a0 = *(const short8*)(ya0 + kt * 32);
        short8 a1 = *(const short8*)(ya1 + kt * 32);
        #pragma unroll
        for (int n = 0; n < 8; ++n) {
            short8 bb = *(const short8*)(wb + n * 4096 + kt * 32);
            acc[0][n] = __builtin_amdgcn_mfma_f32_16x16x32_bf16(a0, bb, acc[0][n], 0, 0, 0);
            acc[1][n] = __builtin_amdgcn_mfma_f32_16x16x32_bf16(a1, bb, acc[1][n], 0, 0, 0);
        }
    }

    // ---- residual prefetch: overlaps the LN epilogue below ----
    uint4 hv[8];
    #pragma unroll
    for (int jj = 0; jj < 8; ++jj) {
        const int idx = jj * 256 + tid;
        const int row = idx >> 5, seg = idx & 31;
        hv[jj] = *(const uint4*)(hin + hbase + (size_t)(t0 + row) * HC + seg * 8);
    }

    // ---- epilogue: bias + split LN(n2) over col halves ----
    float sum[2][4] = {{0, 0, 0, 0}, {0, 0, 0, 0}};
    float sq[2][4] = {{0, 0, 0, 0}, {0, 0, 0, 0}};
    #pragma unroll
    for (int n = 0; n < 8; ++n) {
        const float cb = conv1_b[nh * 128 + n * 16 + lw];
        #pragma unroll
        for (int m = 0; m < 2; ++m)
            #pragma unroll
            for (int r = 0; r < 4; ++r) {
                const float val = acc[m][n][r] + cb;
                acc[m][n][r] = val;
                sum[m][r] += val;
                sq[m][r] += val * val;
            }
    }
    #pragma unroll
    for (int d = 1; d < 16; d <<= 1) {
        #pragma unroll
        for (int m = 0; m < 2; ++m)
            #pragma unroll
            for (int r = 0; r < 4; ++r) {
                sum[m][r] += __shfl_xor(sum[m][r], d, 64);
                sq[m][r] += __shfl_xor(sq[m][r], d, 64);
            }
    }
    if (lw == 0) {
        #pragma unroll
        for (int m = 0; m < 2; ++m)
            #pragma unroll
            for (int r = 0; r < 4; ++r) {
                ssum[mh * 32 + m * 16 + quad * 4 + r][nh] = sum[m][r];
                ssq[mh * 32 + m * 16 + quad * 4 + r][nh] = sq[m][r];
            }
    }
    __syncthreads();

    float mean[2][4], rsv[2][4];
    #pragma unroll
    for (int m = 0; m < 2; ++m)
        #pragma unroll
        for (int r = 0; r < 4; ++r) {
            const int row = mh * 32 + m * 16 + quad * 4 + r;
            const float s = ssum[row][0] + ssum[row][1];
            const float q = ssq[row][0] + ssq[row][1];
            mean[m][r] = s * (1.f / 256.f);
            const float var = q * (1.f / 256.f) - mean[m][r] * mean[m][r];
            rsv[m][r] = rsqrtf(var + 1e-5f);
        }
    #pragma unroll
    for (int n = 0; n < 8; ++n) {
        const int o = nh * 128 + n * 16 + lw;
        const float g2 = n2g[o], b2 = n2b[o];
        #pragma unroll
        for (int m = 0; m < 2; ++m)
            #pragma unroll
            for (int r = 0; r < 4; ++r) {
                const int row = mh * 32 + m * 16 + quad * 4 + r;
                const float y = gelu_f((acc[m][n][r] - mean[m][r]) * rsv[m][r] * g2 + b2);
                ylds[row * 264 + o] = f2bf(y);
            }
    }
    __syncthreads();

    // ---- vectorized residual + store (in-place over yg is safe:
    //      this block's K-loop read only its own rows, all done above) ----
    #pragma unroll
    for (int jj = 0; jj < 8; ++jj) {
        const int idx = jj * 256 + tid;
        const int row = idx >> 5, seg = idx & 31;
        const size_t g = hbase + (size_t)(t0 + row) * HC + seg * 8;
        const uint4 yv = *(const uint4*)(&ylds[row * 264 + seg * 8]);
        uint4 ov;
        ov.x = addbf2(yv.x, hv[jj].x);
        ov.y = addbf2(yv.y, hv[jj].y);
        ov.z = addbf2(yv.z, hv[jj].z);
        ov.w = addbf2(yv.w, hv[jj].w);
        *(uint4*)(hout + g) = ov;
    }
}

// ---------------------------------------------------------- proj+spline ----
__global__ __launch_bounds__(256) void proj_kernel(
    const ushort* __restrict__ hin, const ushort* __restrict__ pwbf,
    const float* __restrict__ projb, const float* __restrict__ x,
    const float* __restrict__ mask, float* __restrict__ out)
{
    __shared__ __align__(16) ushort alds[64 * 264];
    __shared__ float slds[64 * 65];
    __shared__ float red[4];

    const int tid = threadIdx.x;
    const int lane = tid & 63;
    const int wv = tid >> 6;
    const int blk = blockIdx.x;
    const int b = blk >> 6;
    const int t0 = (blk & 63) << 6;
    const size_t hbase = (size_t)b * T_LEN * HC;

    #pragma unroll
    for (int jj = 0; jj < 8; ++jj) {
        const int idx = jj * 256 + tid;
        const int row = idx >> 5, seg = idx & 31;
        short8 v = *(const short8*)(hin + hbase + (size_t)(t0 + row) * HC + seg * 8);
        *(short8*)(&alds[row * 264 + seg * 8]) = v;
    }
    __syncthreads();

    const int lw = lane & 15;
    const int quad = lane >> 4;
    floatx4 acc[4];
    #pragma unroll
    for (int n = 0; n < 4; ++n) acc[n] = (floatx4){0.f, 0.f, 0.f, 0.f};
    #pragma unroll
    for (int kt = 0; kt < 8; ++kt) {
        short8 a = *(short8*)(&alds[(wv * 16 + lw) * 264 + kt * 32 + quad * 8]);
        #pragma unroll
        for (int n = 0; n < 4; ++n) {
            short8 bb = *(const short8*)(pwbf + (n * 16 + lw) * 256 + kt * 32 + quad * 8);
            acc[n] = __builtin_amdgcn_mfma_f32_16x16x32_bf16(a, bb, acc[n], 0, 0, 0);
        }
    }
    #pragma unroll
    for (int n = 0; n < 4; ++n) {
        const int o = n * 16 + lw;
        const float pb = (o < 58) ? projb[o] : 0.f;
        #pragma unroll
        for (int r = 0; r < 4; ++r) {
            const int row = wv * 16 + quad * 4 + r;
            const float mv = mask[b * T_LEN + t0 + row];
            slds[row * 65 + o] = acc[n][r] * mv + pb;
        }
    }
    __syncthreads();

    float contrib = 0.f;
    if (tid < 128) {
        const int pos = tid >> 1;
        const int ch = tid & 1;
        const int t = t0 + pos;
        float sv[29];
        #pragma unroll
        for (int j = 0; j < 29; ++j) sv[j] = slds[pos * 65 + ch * 29 + j];
        const float x1 = x[b * 16384 + (2 + ch) * 4096 + t];

        const float SC = 0.0625f;
        float cwv[11], wdv[10], chv[11], htv[10], dvv[11];
        {
            float u[10];
            float mx = -1e30f;
            #pragma unroll
            for (int j = 0; j < 10; ++j) { u[j] = sv[j] * SC; mx = fmaxf(mx, u[j]); }
            float ssm = 0.f;
            #pragma unroll
            for (int j = 0; j < 10; ++j) { u[j] = expf(u[j] - mx); ssm += u[j]; }
            const float inv = 1.f / ssm;
            float cum = 0.f;
            cwv[0] = -5.f;
            #pragma unroll
            for (int j = 0; j < 10; ++j) {
                cum += 0.001f + 0.99f * u[j] * inv;
                cwv[j + 1] = 10.f * cum - 5.f;
            }
            cwv[10] = 5.f;
            #pragma unroll
            for (int j = 0; j < 10; ++j) wdv[j] = cwv[j + 1] - cwv[j];
        }
        {
            float u[10];
            float mx = -1e30f;
            #pragma unroll
            for (int j = 0; j < 10; ++j) { u[j] = sv[10 + j] * SC; mx = fmaxf(mx, u[j]); }
            float ssm = 0.f;
            #pragma unroll
            for (int j = 0; j < 10; ++j) { u[j] = expf(u[j] - mx); ssm += u[j]; }
            const float inv = 1.f / ssm;
            float cum = 0.f;
            chv[0] = -5.f;
            #pragma unroll
            for (int j = 0; j < 10; ++j) {
                cum += 0.001f + 0.99f * u[j] * inv;
                chv[j + 1] = 10.f * cum - 5.f;
            }
            chv[10] = 5.f;
            #pragma unroll
            for (int j = 0; j < 10; ++j) htv[j] = chv[j + 1] - chv[j];
        }
        dvv[0] = 1.f;
        dvv[10] = 1.f;
        #pragma unroll
        for (int j = 1; j <= 9; ++j) dvv[j] = 0.001f + softplus_f(sv[19 + j]);

        const bool inside = (x1 >= -5.f) && (x1 <= 5.f);
        const float xc = fminf(fmaxf(x1, -5.f), 5.f);
        float in_cw = cwv[0], in_w = wdv[0], in_ch = chv[0], in_h = htv[0];
        float dk = dvv[0], dk1 = dvv[1];
        #pragma unroll
        for (int j = 1; j < 10; ++j) {
            const bool ge = (xc >= cwv[j]);
            in_cw = ge ? cwv[j] : in_cw;
            in_w  = ge ? wdv[j] : in_w;
            in_ch = ge ? chv[j] : in_ch;
            in_h  = ge ? htv[j] : in_h;
            dk    = ge ? dvv[j] : dk;
            dk1   = ge ? dvv[j + 1] : dk1;
        }
        const float th = (xc - in_cw) / in_w;
        const float t1m = th * (1.f - th);
        const float dl = in_h / in_w;
        const float num = in_h * (dl * th * th + dk * t1m);
        const float den = dl + (dk + dk1 - 2.f * dl) * t1m;
        float yv = in_ch + num / den;
        const float omt = 1.f - th;
        const float dnum = dl * dl * (dk1 * th * th + 2.f * dl * t1m + dk * omt * omt);
        float lad = logf(dnum) - 2.f * logf(den);
        if (!inside) { yv = x1; lad = 0.f; }
        const float mv = mask[b * T_LEN + t];
        out[b * 16384 + (2 + ch) * 4096 + t] = yv * mv;
        contrib = lad * mv;
    }
    #pragma unroll
    for (int d = 32; d > 0; d >>= 1) contrib += __shfl_xor(contrib, d, 64);
    if (lane == 0) red[wv] = contrib;
    __syncthreads();
    if (tid == 0) atomicAdd(out + OUT_ELEMS + b, red[0] + red[1] + red[2] + red[3]);
}

// -------------------------------------------------------------- launch ----
extern "C" void kernel_launch(void* const* d_in, const int* in_sizes, int n_in,
                              void* d_out, int out_size, void* d_ws, size_t ws_size,
                              hipStream_t stream) {
    const float* x      = (const float*)d_in[0];
    const float* mask   = (const float*)d_in[1];
    const float* pre_w  = (const float*)d_in[2];
    const float* pre_b  = (const float*)d_in[3];
    const float* sep_w  = (const float*)d_in[4];
    const float* sep_b  = (const float*)d_in[5];
    const float* conv1w = (const float*)d_in[6];
    const float* conv1b = (const float*)d_in[7];
    const float* n1g    = (const float*)d_in[8];
    const float* n1b    = (const float*)d_in[9];
    const float* n2g    = (const float*)d_in[10];
    const float* n2b    = (const float*)d_in[11];
    const float* projw  = (const float*)d_in[12];
    const float* projb  = (const float*)d_in[13];
    float* out = (float*)d_out;

    ushort* h0   = (ushort*)d_ws;
    ushort* h1   = h0 + (size_t)NPOS * HC;
    ushort* wbf  = h1 + (size_t)NPOS * HC;
    ushort* pwbf = wbf + 4 * 256 * 256;

    prep_kernel<<<1088, 256, 0, stream>>>(conv1w, projw, wbf, pwbf);
    pre_kernel<<<NPOS / 2, 256, 0, stream>>>(x, mask, pre_w, pre_b, h0, out);

    int dil = 1;
    ushort* src = h0;   // current h
    ushort* dst = h1;   // y staging, then overwritten in-place with h_next
    for (int i = 0; i < 4; ++i) {
        dwln_kernel<<<4096, 256, 0, stream>>>(src, dst,
            sep_w + i * 768, sep_b + i * 256,
            n1g + i * 256, n1b + i * 256, mask, dil);
        gemm_kernel<<<2048, 256, 0, stream>>>(dst, src, dst, wbf + i * 65536,
            conv1b + i * 256, n2g + i * 256, n2b + i * 256);
        dil *= 3;
        ushort* tmp = src; src = dst; dst = tmp;
    }
    proj_kernel<<<2048, 256, 0, stream>>>(src, pwbf, projb, x, mask, out);
}